// Round 1
// baseline (319.976 us; speedup 1.0000x reference)
//
#include <hip/hip_runtime.h>
#include <hip/hip_bf16.h>

#define B_ 2
#define C_ 256
#define N_ 110592
#define CN_ ((size_t)C_ * N_)

typedef __attribute__((ext_vector_type(4))) float f32x4;
typedef __attribute__((ext_vector_type(8))) short bf16x8;
typedef __attribute__((ext_vector_type(4))) short bf16x4;

__device__ __forceinline__ short f2bf(float f) {
    union { float f; unsigned u; } v; v.f = f;
    unsigned r = (v.u + 0x7fffu + ((v.u >> 16) & 1u)) >> 16;
    return (short)(r & 0xffffu);
}

// ---------------- Pass 1: raw Gram (split-K) + rowsums ----------------
// grid (nck, B), 512 threads. Each block: chunk of K spatial elems.
// Wave tile: 64c x 128d of the 256x256 Gram. LDS tile: 256 ch x 64 n bf16.
__global__ __launch_bounds__(512, 2) void k_gram(
        const float* __restrict__ x, float* __restrict__ part,
        float* __restrict__ rspart, int Kc, int nck) {
    __shared__ short Xs[256 * 64];       // swizzled rows of 128B
    __shared__ float rs_s[256];
    const int t = threadIdx.x;
    const int lane = t & 63, wave = t >> 6;
    const int chunk = blockIdx.x, b = blockIdx.y;
    const int k0 = chunk * Kc;
    if (t < 256) rs_s[t] = 0.f;

    f32x4 acc[4][8];
#pragma unroll
    for (int i = 0; i < 4; ++i)
#pragma unroll
        for (int j = 0; j < 8; ++j) acc[i][j] = f32x4{0.f, 0.f, 0.f, 0.f};

    const int cw0 = (wave & 3) * 64;     // c range of this wave
    const int dw0 = (wave >> 2) * 128;   // d range of this wave
    const float* xb = x + (size_t)b * CN_;
    const int r16 = lane & 15, g16 = lane >> 4;

    for (int ks = 0; ks < Kc; ks += 64) {
        __syncthreads();
        // stage 256x64 f32 -> bf16 LDS, and accumulate rowsums (f32, exact)
#pragma unroll
        for (int i = 0; i < 8; ++i) {
            int f = i * 512 + t;
            int c = f >> 4;
            int s4 = f & 15;
            int kg = k0 + ks + s4 * 4;
            f32x4 v = {0.f, 0.f, 0.f, 0.f};
            if (kg < N_) v = *(const f32x4*)(xb + (size_t)c * N_ + kg);
            float rsum = v.x + v.y + v.z + v.w;
            rsum += __shfl_xor(rsum, 1);
            rsum += __shfl_xor(rsum, 2);
            rsum += __shfl_xor(rsum, 4);
            rsum += __shfl_xor(rsum, 8);
            if ((t & 15) == 0) rs_s[c] += rsum;   // single writer per c
            bf16x4 h;
            h.x = f2bf(v.x); h.y = f2bf(v.y); h.z = f2bf(v.z); h.w = f2bf(v.w);
            int byte = (c * 128 + s4 * 8) ^ ((c & 7) << 4);
            *(bf16x4*)((char*)Xs + byte) = h;
        }
        __syncthreads();
        // 64 n = 2 K-steps of 32
#pragma unroll
        for (int k2 = 0; k2 < 2; ++k2) {
            bf16x8 afr[4], bfr[8];
#pragma unroll
            for (int ct = 0; ct < 4; ++ct) {
                int row = cw0 + ct * 16 + r16;
                afr[ct] = *(const bf16x8*)((const char*)Xs +
                    ((row * 128 + k2 * 64 + g16 * 16) ^ ((row & 7) << 4)));
            }
#pragma unroll
            for (int dt = 0; dt < 8; ++dt) {
                int row = dw0 + dt * 16 + r16;
                bfr[dt] = *(const bf16x8*)((const char*)Xs +
                    ((row * 128 + k2 * 64 + g16 * 16) ^ ((row & 7) << 4)));
            }
#pragma unroll
            for (int ct = 0; ct < 4; ++ct)
#pragma unroll
                for (int dt = 0; dt < 8; ++dt)
                    acc[ct][dt] = __builtin_amdgcn_mfma_f32_16x16x32_bf16(
                        afr[ct], bfr[dt], acc[ct][dt], 0, 0, 0);
        }
    }
    __syncthreads();
    float* pp = part + ((size_t)b * nck + chunk) * (C_ * C_);
#pragma unroll
    for (int ct = 0; ct < 4; ++ct)
#pragma unroll
        for (int dt = 0; dt < 8; ++dt) {
            int d = dw0 + dt * 16 + r16;
#pragma unroll
            for (int rr = 0; rr < 4; ++rr) {
                int c = cw0 + ct * 16 + g16 * 4 + rr;
                pp[(size_t)c * C_ + d] = acc[ct][dt][rr];
            }
        }
    if (t < 256) rspart[((size_t)b * nck + chunk) * C_ + t] = rs_s[t];
}

// ---------------- reduce partial Grams ----------------
__global__ void k_reduce(const float* __restrict__ part, float* __restrict__ Graw,
                         int nck) {
    int bid = blockIdx.x;          // b*256 + c
    int b = bid >> 8, c = bid & 255;
    int d = threadIdx.x;
    float s = 0.f;
    for (int p = 0; p < nck; ++p)
        s += part[(((size_t)b * nck + p) * (C_ * C_)) + (size_t)c * C_ + d];
    Graw[((size_t)b * C_ + c) * C_ + d] = s;
}

// ---------------- stats ----------------
__global__ void k_stats(const float* __restrict__ rspart, const float* __restrict__ Graw,
                        float* __restrict__ mean, float* __restrict__ rsig, int nck) {
    int t = threadIdx.x;           // 0..511 = b*256+c
    int b = t >> 8, c = t & 255;
    float s = 0.f;
    for (int p = 0; p < nck; ++p) s += rspart[((size_t)b * nck + p) * C_ + c];
    float m = s / (float)N_;
    float g = Graw[((size_t)b * C_ + c) * C_ + c];
    float var = g / (float)N_ - m * m;
    mean[t] = m;
    rsig[t] = rsqrtf(var + 1e-5f);
}

// ---------------- transpose Wk ----------------
__global__ void k_wkt(const float* __restrict__ Wk, float* __restrict__ WkT) {
    int e = blockIdx.x, d = threadIdx.x;
    WkT[(size_t)e * C_ + d] = Wk[(size_t)d * C_ + e];
}

// ---------------- P = Wq * Gn  (Gn normalized on the fly) ----------------
__global__ void k_gemm1(const float* __restrict__ Wq, const float* __restrict__ Graw,
                        const float* __restrict__ mean, const float* __restrict__ rsig,
                        float* __restrict__ P) {
    int bid = blockIdx.x; int b = bid >> 8, c = bid & 255; int d = threadIdx.x;
    const float* G = Graw + (size_t)b * C_ * C_;
    const float* mb = mean + b * C_;
    const float* rb = rsig + b * C_;
    float md = mb[d], rd = rb[d];
    float a1 = 0.f, a2 = 0.f;
    for (int e = 0; e < C_; ++e) {
        float w = Wq[(size_t)c * C_ + e] * rb[e];
        a1 += w * G[(size_t)e * C_ + d];
        a2 += w * mb[e];
    }
    P[((size_t)b * C_ + c) * C_ + d] = rd * a1 - (float)N_ * md * rd * a2;
}

// ---------------- S = P * Wk^T + N bq bk^T ----------------
__global__ void k_gemm2(const float* __restrict__ P, const float* __restrict__ WkT,
                        const float* __restrict__ bq, const float* __restrict__ bk,
                        float* __restrict__ S) {
    int bid = blockIdx.x; int b = bid >> 8, c = bid & 255; int d = threadIdx.x;
    const float* Pr = P + ((size_t)b * C_ + c) * C_;
    float a = 0.f;
    for (int e = 0; e < C_; ++e)
        a += Pr[e] * WkT[(size_t)e * C_ + d];
    S[((size_t)b * C_ + c) * C_ + d] = a + (float)N_ * bq[c] * bk[d];
}

// ---------------- atten = softmax(S)/16 + outer/16 ----------------
__global__ void k_softmax(const float* __restrict__ S, const float* __restrict__ outer,
                          float* __restrict__ atten) {
    __shared__ float red[8];
    int bid = blockIdx.x; int b = bid >> 8, c = bid & 255; int d = threadIdx.x;
    int lane = d & 63, w = d >> 6;
    float v = S[((size_t)b * C_ + c) * C_ + d];
    float m = v;
    for (int off = 32; off; off >>= 1) m = fmaxf(m, __shfl_xor(m, off));
    if (lane == 0) red[w] = m;
    __syncthreads();
    m = fmaxf(fmaxf(red[0], red[1]), fmaxf(red[2], red[3]));
    float e = __expf(v - m);
    float s = e;
    for (int off = 32; off; off >>= 1) s += __shfl_xor(s, off);
    if (lane == 0) red[4 + w] = s;
    __syncthreads();
    s = red[4] + red[5] + red[6] + red[7];
    atten[((size_t)b * C_ + c) * C_ + d] = e / (s * 16.f) + outer[(size_t)c * C_ + d] * 0.0625f;
}

// ---------------- A = (atten*Wv + I) * diag(rsig) (bf16), beta ----------------
__global__ void k_gemm3(const float* __restrict__ atten, const float* __restrict__ Wv,
                        const float* __restrict__ bv, const float* __restrict__ mean,
                        const float* __restrict__ rsig, short* __restrict__ Abf,
                        float* __restrict__ beta) {
    __shared__ float red[4];
    int bid = blockIdx.x; int b = bid >> 8, c = bid & 255; int g = threadIdx.x;
    int lane = g & 63, w = g >> 6;
    const float* at = atten + ((size_t)b * C_ + c) * C_;
    float a = 0.f;
    for (int d = 0; d < C_; ++d)
        a += at[d] * Wv[(size_t)d * C_ + g];
    float Ag = (a + ((g == c) ? 1.f : 0.f)) * rsig[b * C_ + g];
    Abf[((size_t)b * C_ + c) * C_ + g] = f2bf(Ag);
    float u = at[g] * bv[g] - Ag * mean[b * C_ + g];   // beta = sum(u)
    for (int off = 32; off; off >>= 1) u += __shfl_xor(u, off);
    if (lane == 0) red[w] = u;
    __syncthreads();
    if (g == 0) beta[b * C_ + c] = red[0] + red[1] + red[2] + red[3];
}

// ---------------- Pass 2: out = A * x + beta ----------------
// grid (432, B), 512 threads. A (256x256 bf16) in LDS swizzled; each wave
// computes all 256 c for its 32 n; x fragments loaded direct from global.
__global__ __launch_bounds__(512, 2) void k_out(
        const float* __restrict__ x, const short* __restrict__ Abf,
        const float* __restrict__ beta, float* __restrict__ out) {
    __shared__ short As[C_ * C_];      // 128 KB
    __shared__ float beta_s[C_];
    const int t = threadIdx.x, lane = t & 63, wave = t >> 6;
    const int nb = blockIdx.x, b = blockIdx.y;
    const short* Ab = Abf + (size_t)b * C_ * C_;
#pragma unroll
    for (int i = 0; i < 16; ++i) {
        int slot = i * 512 + t;
        int c = slot >> 5, s = slot & 31;
        int src = c * 512 + s * 16;
        *(f32x4*)((char*)As + (src ^ ((c & 15) << 4))) =
            *(const f32x4*)((const char*)Ab + src);
    }
    if (t < 256) beta_s[t] = beta[b * C_ + t];
    __syncthreads();

    const int col = lane & 15, g16 = lane >> 4;
    const int n0 = nb * 256 + wave * 32;
    const float* xb = x + (size_t)b * CN_;

    f32x4 acc[16][2];
#pragma unroll
    for (int i = 0; i < 16; ++i) {
        acc[i][0] = f32x4{0.f, 0.f, 0.f, 0.f};
        acc[i][1] = f32x4{0.f, 0.f, 0.f, 0.f};
    }
    float pf[2][16];
#pragma unroll
    for (int nt = 0; nt < 2; ++nt)
#pragma unroll
        for (int j = 0; j < 8; ++j)
            pf[0][nt * 8 + j] = xb[(size_t)(g16 * 8 + j) * N_ + (n0 + nt * 16 + col)];
#pragma unroll
    for (int ks = 0; ks < 8; ++ks) {
        if (ks < 7) {
#pragma unroll
            for (int nt = 0; nt < 2; ++nt)
#pragma unroll
                for (int j = 0; j < 8; ++j)
                    pf[(ks + 1) & 1][nt * 8 + j] =
                        xb[(size_t)((ks + 1) * 32 + g16 * 8 + j) * N_ + (n0 + nt * 16 + col)];
        }
        bf16x8 bfr[2];
#pragma unroll
        for (int nt = 0; nt < 2; ++nt)
#pragma unroll
            for (int j = 0; j < 8; ++j)
                bfr[nt][j] = f2bf(pf[ks & 1][nt * 8 + j]);
#pragma unroll
        for (int ct = 0; ct < 16; ++ct) {
            int row = ct * 16 + col;
            bf16x8 afr = *(const bf16x8*)((const char*)As +
                ((row * 512 + ks * 64 + g16 * 16) ^ ((row & 15) << 4)));
            acc[ct][0] = __builtin_amdgcn_mfma_f32_16x16x32_bf16(afr, bfr[0], acc[ct][0], 0, 0, 0);
            acc[ct][1] = __builtin_amdgcn_mfma_f32_16x16x32_bf16(afr, bfr[1], acc[ct][1], 0, 0, 0);
        }
    }
    float* ob = out + (size_t)b * CN_;
#pragma unroll
    for (int ct = 0; ct < 16; ++ct)
#pragma unroll
        for (int nt = 0; nt < 2; ++nt) {
            int n = n0 + nt * 16 + col;
#pragma unroll
            for (int rr = 0; rr < 4; ++rr) {
                int c = ct * 16 + g16 * 4 + rr;
                ob[(size_t)c * N_ + n] = acc[ct][nt][rr] + beta_s[c];
            }
        }
}

extern "C" void kernel_launch(void* const* d_in, const int* in_sizes, int n_in,
                              void* d_out, int out_size, void* d_ws, size_t ws_size,
                              hipStream_t stream) {
    (void)in_sizes; (void)n_in; (void)out_size;
    const float* x     = (const float*)d_in[0];
    const float* Wq    = (const float*)d_in[1];
    const float* bq    = (const float*)d_in[2];
    const float* Wk    = (const float*)d_in[3];
    const float* bk    = (const float*)d_in[4];
    const float* Wv    = (const float*)d_in[5];
    const float* bv    = (const float*)d_in[6];
    const float* outer = (const float*)d_in[7];
    float* out = (float*)d_out;

    char* w = (char*)d_ws;
    float* mean   = (float*)(w);
    float* rsig   = (float*)(w + 2048);
    float* beta   = (float*)(w + 4096);
    float* Graw   = (float*)(w + 8192);
    float* P      = (float*)(w + 8192 + 1 * 524288);
    float* S      = (float*)(w + 8192 + 2 * 524288);
    float* atten  = (float*)(w + 8192 + 3 * 524288);
    float* WkT    = (float*)(w + 8192 + 4 * 524288);
    short* Abf    = (short*)(w + 8192 + 4 * 524288 + 262144);
    float* rspart = (float*)(w + 8192 + 4 * 524288 + 2 * 262144);
    float* part   = (float*)(w + 8192 + 4 * 524288 + 3 * 262144);
    size_t fixed = 8192 + 4 * 524288 + 3 * 262144;

    size_t avail = ws_size > fixed ? ws_size - fixed : 0;
    long long nckl = (long long)(avail / ((size_t)B_ * C_ * C_ * 4));
    int nck = (int)(nckl < 1 ? 1 : (nckl > 128 ? 128 : nckl));
    int Kc = ((N_ + nck * 64 - 1) / (nck * 64)) * 64;   // K-chunk, mult of 64
    nck = (N_ + Kc - 1) / Kc;

    k_gram   <<<dim3(nck, B_), 512, 0, stream>>>(x, part, rspart, Kc, nck);
    k_reduce <<<dim3(B_ * C_), 256, 0, stream>>>(part, Graw, nck);
    k_stats  <<<dim3(1), 512, 0, stream>>>(rspart, Graw, mean, rsig, nck);
    k_wkt    <<<dim3(C_), C_, 0, stream>>>(Wk, WkT);
    k_gemm1  <<<dim3(B_ * C_), C_, 0, stream>>>(Wq, Graw, mean, rsig, P);
    k_gemm2  <<<dim3(B_ * C_), C_, 0, stream>>>(P, WkT, bq, bk, S);
    k_softmax<<<dim3(B_ * C_), C_, 0, stream>>>(S, outer, atten);
    k_gemm3  <<<dim3(B_ * C_), C_, 0, stream>>>(atten, Wv, bv, mean, rsig, Abf, beta);
    k_out    <<<dim3(N_ / 256, B_), 512, 0, stream>>>(x, Abf, beta, out);
}